// Round 7
// baseline (308.072 us; speedup 1.0000x reference)
//
#include <hip/hip_runtime.h>
#include <hip/hip_bf16.h>

// ---------------------------------------------------------------------------
// GHN (float32 I/O): encode (3 gathered GEMMs, bf16 MFMA, f32 acc)
//   -> 2-layer GCN -> decode (gathered GEMMs, MFMA) -> f32
// R7: k_enc targets cold-read concurrency (the surviving theory after 4 flat
// variants): (1) conv K-split 16->32 slots x 8 mgroups = 256 blocks -> full
// CU coverage at unchanged B traffic; (2) __launch_bounds__(256,2) + explicit
// 12-load-first inner loop to deepen per-wave outstanding loads (VGPR was 56
// -> ~6 loads in flight; target 110+).
// k_z1 (ns=32) / k_propA / k_propF0 / k_propF1 / k_dec: R6-exact (299.3us).
// ---------------------------------------------------------------------------

typedef __attribute__((ext_vector_type(8))) __bf16 bf16x8;
typedef __attribute__((ext_vector_type(4))) float f32x4;

#define MFMA16(a,b,c) __builtin_amdgcn_mfma_f32_16x16x32_bf16((a),(b),(c),0,0,0)

__device__ __forceinline__ bf16x8 cvt8(const float* p) {
    float4 a = *(const float4*)p;
    float4 b = *(const float4*)(p + 4);
    bf16x8 r;
    r[0]=(__bf16)a.x; r[1]=(__bf16)a.y; r[2]=(__bf16)a.z; r[3]=(__bf16)a.w;
    r[4]=(__bf16)b.x; r[5]=(__bf16)b.y; r[6]=(__bf16)b.z; r[7]=(__bf16)b.w;
    return r;
}

__device__ __forceinline__ bf16x8 pack8(float4 a, float4 b) {
    bf16x8 r;
    r[0]=(__bf16)a.x; r[1]=(__bf16)a.y; r[2]=(__bf16)a.z; r[3]=(__bf16)a.w;
    r[4]=(__bf16)b.x; r[5]=(__bf16)b.y; r[6]=(__bf16)b.z; r[7]=(__bf16)b.w;
    return r;
}

// single-mtile direct tile (bias encoder)
template<int KSTEPS, int DIV>
__device__ __forceinline__ void enc_tile(const float* Ar,
                                         const float* B0,
                                         const float* B1,
                                         int kw, int kg, f32x4& acc0, f32x4& acc1)
{
#pragma unroll
    for (int s = 0; s < KSTEPS; ++s) {
        int k = kw + s*32 + kg*8;
        int col = DIV ? (k + (k/DIV)*DIV) : k;
        bf16x8 a  = cvt8(Ar + k);
        bf16x8 b0 = cvt8(B0 + col);
        bf16x8 b1 = cvt8(B1 + col);
        acc0 = MFMA16(a, b0, acc0);
        acc1 = MFMA16(a, b1, acc1);
    }
}

// 4-mtile tile, load-first form: all 12 float4-pairs of a K-step are issued
// as independent loads before any convert/MFMA (scheduler can hoist across
// the unrolled iterations given VGPR headroom).
template<int KSTEPS, int DIV>
__device__ __forceinline__ void enc_tile4(const float* Abase, size_t AST,
                                          const float* B0, const float* B1,
                                          int kw, int n16, int kg,
                                          f32x4 (&acc0)[4], f32x4 (&acc1)[4])
{
    const float* Ar0 = Abase + (size_t)(n16)      * AST;
    const float* Ar1 = Abase + (size_t)(16 + n16) * AST;
    const float* Ar2 = Abase + (size_t)(32 + n16) * AST;
    const float* Ar3 = Abase + (size_t)(48 + n16) * AST;
#pragma unroll
    for (int s = 0; s < KSTEPS; ++s) {
        int k = kw + s*32 + kg*8;
        int col = k + (k/DIV)*DIV;
        // ---- issue all loads (12 x dwordx4), no consumers yet
        float4 b0a = *(const float4*)(B0 + col);
        float4 b0b = *(const float4*)(B0 + col + 4);
        float4 b1a = *(const float4*)(B1 + col);
        float4 b1b = *(const float4*)(B1 + col + 4);
        float4 a0a = *(const float4*)(Ar0 + k);
        float4 a0b = *(const float4*)(Ar0 + k + 4);
        float4 a1a = *(const float4*)(Ar1 + k);
        float4 a1b = *(const float4*)(Ar1 + k + 4);
        float4 a2a = *(const float4*)(Ar2 + k);
        float4 a2b = *(const float4*)(Ar2 + k + 4);
        float4 a3a = *(const float4*)(Ar3 + k);
        float4 a3b = *(const float4*)(Ar3 + k + 4);
        // ---- convert + MFMA
        bf16x8 b0 = pack8(b0a, b0b);
        bf16x8 b1 = pack8(b1a, b1b);
        bf16x8 a0 = pack8(a0a, a0b);
        bf16x8 a1 = pack8(a1a, a1b);
        bf16x8 a2 = pack8(a2a, a2b);
        bf16x8 a3 = pack8(a3a, a3b);
        acc0[0] = MFMA16(a0, b0, acc0[0]);  acc1[0] = MFMA16(a0, b1, acc1[0]);
        acc0[1] = MFMA16(a1, b0, acc0[1]);  acc1[1] = MFMA16(a1, b1, acc1[1]);
        acc0[2] = MFMA16(a2, b0, acc0[2]);  acc1[2] = MFMA16(a2, b1, acc1[2]);
        acc0[3] = MFMA16(a3, b0, acc0[3]);  acc1[3] = MFMA16(a3, b1, acc1[3]);
    }
}

// ---------------------------------------------------------------------------
// k_enc: conv 256 blocks (8 mg x 32 ks, id = mg*32+ks), lin 16, bias 16,
// dinv 64 -> grid 352. 256 thr / 4 waves. LDS reduce 32 KB.
// P has 32 K-slots for conv (lin uses 0..3, bias slot 0).
// ---------------------------------------------------------------------------
__global__ __launch_bounds__(256, 2) void k_enc(
    const float* __restrict__ conv_w,
    const float* __restrict__ lin_w,
    const float* __restrict__ bias_w,
    const float* __restrict__ conv_enc_w,
    const float* __restrict__ lin_enc_w,
    const float* __restrict__ bias_enc_w,
    const int* __restrict__ adj,
    float* __restrict__ P, float* __restrict__ dinv)
{
    int b = blockIdx.x, tid = threadIdx.x;
    int w = tid >> 6, lane = tid & 63;
    int n16 = lane & 15, kg = lane >> 4;

    if (b >= 288) {  // ---- dinv rows (64 blocks)
        int wid = (b - 288)*4 + w;
        for (int r = wid; r < 1025; r += 256) {
            const int* row = adj + (size_t)r*1025;
            int s = 0;
#pragma unroll
            for (int i = 0; i <= 16; ++i) {
                int j = lane + i*64;
                if (j < 1025) s += row[j];
            }
#pragma unroll
            for (int off = 32; off; off >>= 1) s += __shfl_xor(s, off, 64);
            if (lane == 0) dinv[r] = 1.0f / sqrtf((float)s + 1.0f);
        }
        return;
    }

    __shared__ float R[4*4*512];   // 32 KB: [wave][mtile][(kg*4+r)*32+col]

    if (b < 272) {   // ---- conv (b<256) & lin (256<=b<272): 4-mtile path
        f32x4 acc0[4] = {{0,0,0,0},{0,0,0,0},{0,0,0,0},{0,0,0,0}};
        f32x4 acc1[4] = {{0,0,0,0},{0,0,0,0},{0,0,0,0},{0,0,0,0}};
        int slot, nodebase, mbase;
        if (b < 256) {            // conv: M=512, K=36864; 32 ks x 8 mg
            int mg = b >> 5, ks = b & 31;
            slot = ks; nodebase = 0; mbase = mg*4;
            const float* B0 = conv_enc_w + (size_t)n16*147456;
            const float* B1 = conv_enc_w + (size_t)(16+n16)*147456;
            enc_tile4<9,576>(conv_w + (size_t)mbase*16*36864, 36864,
                             B0, B1, ks*1152 + w*288, n16, kg, acc0, acc1);
        } else {                  // lin: M=256, K=4096; 4 mg x 4 ks
            int bb = b - 256; int mg = bb >> 2, ks = bb & 3;
            slot = ks; nodebase = 512; mbase = mg*4;
            const float* B0 = lin_enc_w + (size_t)n16*16384;
            const float* B1 = lin_enc_w + (size_t)(16+n16)*16384;
            enc_tile4<8,64>(lin_w + (size_t)mbase*16*4096, 4096,
                            B0, B1, ks*1024 + w*256, n16, kg, acc0, acc1);
        }
#pragma unroll
        for (int m = 0; m < 4; ++m)
#pragma unroll
            for (int r = 0; r < 4; ++r) {
                R[((w*4 + m)*16 + kg*4 + r)*32 + n16]      = acc0[m][r];
                R[((w*4 + m)*16 + kg*4 + r)*32 + 16 + n16] = acc1[m][r];
            }
        __syncthreads();
        for (int e = tid; e < 2048; e += 256) {
            int m = e >> 9, wi = e & 511;
            float s = R[m*512 + wi]        + R[(4+m)*512 + wi]
                    + R[(8+m)*512 + wi]    + R[(12+m)*512 + wi];
            int nl = wi >> 5, h = wi & 31;
            int node = nodebase + (mbase + m)*16 + nl;
            P[((size_t)slot*1024 + node)*32 + h] = s;
        }
    } else {         // ---- bias (272<=b<288): single-mtile path
        int mtile = b - 272;
        f32x4 acc0 = {0,0,0,0}, acc1 = {0,0,0,0};
        if (w < 2) {
            const float* Ar = bias_w     + (size_t)(mtile*16 + n16)*64;
            const float* B0 = bias_enc_w + (size_t)n16*128;
            const float* B1 = bias_enc_w + (size_t)(16+n16)*128;
            enc_tile<1,0>(Ar, B0, B1, w*32, kg, acc0, acc1);
        }
#pragma unroll
        for (int r = 0; r < 4; ++r) {
            R[(w*16 + kg*4 + r)*32 + n16]      = acc0[r];
            R[(w*16 + kg*4 + r)*32 + 16 + n16] = acc1[r];
        }
        __syncthreads();
        for (int e = tid; e < 512; e += 256) {
            float s = R[e] + R[512+e] + R[1024+e] + R[1536+e];
            int nl = e >> 5, h = e & 31;
            int node = 768 + mtile*16 + nl;
            P[(size_t)node*32 + h] = s;          // slot 0
        }
    }
}

// ---------------------------------------------------------------------------
// k_z1: R6-exact except conv ns = 32 (K-slot count doubled)
// ---------------------------------------------------------------------------
__global__ __launch_bounds__(256) void k_z1(
    const float* __restrict__ P,
    const float* __restrict__ conv_enc_b,
    const float* __restrict__ lin_enc_b,
    const float* __restrict__ bias_enc_b,
    const float* __restrict__ embed_tab,
    const int* __restrict__ prims,
    const float* __restrict__ gcn_w1,
    const float* __restrict__ dinv,
    float* __restrict__ Z1s,
    float* __restrict__ red)
{
    __shared__ float El[8*32], Ml[8*32];
    int tid = threadIdx.x;
    int i0 = blockIdx.x * 8;

    for (int idx = blockIdx.x*256 + tid; idx < 98400; idx += 129*256)
        red[idx] = 0.f;

    {
        int rl = tid >> 5, h = tid & 31;
        int i = i0 + rl;
        if (i < 1025) {
            float e, m;
            if (i == 0) { e = 1.0f; m = 1.0f; }
            else {
                int node = i - 1;
                int ns; float bias;
                if (node < 512)      { ns = 32; bias = conv_enc_b[h]; }
                else if (node < 768) { ns = 4;  bias = lin_enc_b[h];  }
                else                 { ns = 1;  bias = bias_enc_b[h]; }
                float s = bias;
                for (int sl = 0; sl < ns; ++sl)
                    s += P[((size_t)sl*1024 + node)*32 + h];
                e = s;
                m = embed_tab[prims[node]*32 + h];
            }
            El[rl*32+h] = e; Ml[rl*32+h] = m;
        }
    }
    __syncthreads();
    if (tid < 192) {
        int rl = tid / 24, c4 = tid % 24;
        int i = i0 + rl;
        if (i < 1025) {
            float a0=0,a1=0,a2=0,a3=0;
            for (int h = 0; h < 32; ++h) {
                float e = El[rl*32+h], m = Ml[rl*32+h];
                float4 wa = *(const float4*)(gcn_w1 + h*96 + c4*4);
                float4 wb = *(const float4*)(gcn_w1 + (h+32)*96 + c4*4);
                float4 wc = *(const float4*)(gcn_w1 + (h+64)*96 + c4*4);
                a0 += e*(wa.x+wb.x) + m*wc.x;
                a1 += e*(wa.y+wb.y) + m*wc.y;
                a2 += e*(wa.z+wb.z) + m*wc.z;
                a3 += e*(wa.w+wb.w) + m*wc.w;
            }
            float di = dinv[i];
            float* o = Z1s + (size_t)i*96 + c4*4;
            o[0] = di*a0; o[1] = di*a1; o[2] = di*a2; o[3] = di*a3;
        }
    }
}

// ---------------------------------------------------------------------------
// k_propA: R6-exact
// ---------------------------------------------------------------------------
__global__ __launch_bounds__(256) void k_propA(
    const float* __restrict__ Zs, const int* __restrict__ adj,
    float* __restrict__ red)
{
    __shared__ float adjf[20*132];
    int tid = threadIdx.x;
    int jc = blockIdx.x & 7, it = blockIdx.x >> 3;
    int i0 = it * 20;
    int j0 = jc * 128;
    int jlen = (jc == 7) ? 129 : 128;

    for (int idx = tid; idx < 20*132; idx += 256) {
        int row = idx / 132, c = idx % 132;
        int i = i0 + row, j = j0 + c;
        if (c < jlen && i < 1025)
            adjf[row*132 + c] = (float)adj[(size_t)i*1025 + j]
                                + (i == j ? 1.0f : 0.0f);
    }
    __syncthreads();

    if (tid < 240) {
        int c4 = tid % 24, ig = tid / 24;
        int rA = i0 + ig, rB = i0 + ig + 10;
        float accA[4] = {0,0,0,0}, accB[4] = {0,0,0,0};
        for (int jj = 0; jj < jlen; ++jj) {
            const float4 z = *(const float4*)(Zs + (size_t)(j0+jj)*96 + c4*4);
            float aA = adjf[ig*132 + jj];
            float aB = adjf[(ig+10)*132 + jj];
            accA[0] += aA*z.x; accA[1] += aA*z.y;
            accA[2] += aA*z.z; accA[3] += aA*z.w;
            accB[0] += aB*z.x; accB[1] += aB*z.y;
            accB[2] += aB*z.z; accB[3] += aB*z.w;
        }
        if (rA < 1025) {
            float* o = red + (size_t)rA*96 + c4*4;
            atomicAdd(o+0, accA[0]); atomicAdd(o+1, accA[1]);
            atomicAdd(o+2, accA[2]); atomicAdd(o+3, accA[3]);
        }
        if (rB < 1025) {
            float* o = red + (size_t)rB*96 + c4*4;
            atomicAdd(o+0, accB[0]); atomicAdd(o+1, accB[1]);
            atomicAdd(o+2, accB[2]); atomicAdd(o+3, accB[3]);
        }
    }
}

// ---------------------------------------------------------------------------
// k_propF0: R6-exact
// ---------------------------------------------------------------------------
__global__ __launch_bounds__(256) void k_propF0(
    const float* __restrict__ red, const float* __restrict__ dinv,
    const float* __restrict__ gcn_w2,
    float* __restrict__ Z2s, float* __restrict__ redz)
{
    __shared__ float redl[5*96];
    int tid = threadIdx.x;
    int i0 = blockIdx.x * 5;
    for (int idx = tid; idx < 5*96; idx += 256) {
        int r = idx / 96, c = idx % 96;
        int i = i0 + r;
        if (i < 1025) {
            redl[idx] = red[(size_t)i*96 + c];
            redz[(size_t)i*96 + c] = 0.f;
        }
    }
    __syncthreads();
    if (tid < 120) {
        int c4 = tid % 24, ig = tid / 24;
        int i = i0 + ig;
        if (i < 1025) {
            float di = dinv[i];
            float o0=0,o1=0,o2=0,o3=0;
            for (int c = 0; c < 96; ++c) {
                float hv = redl[ig*96 + c] * di; hv = hv > 0.f ? hv : 0.f;
                float4 w2 = *(const float4*)(gcn_w2 + c*96 + c4*4);
                o0 += hv*w2.x; o1 += hv*w2.y; o2 += hv*w2.z; o3 += hv*w2.w;
            }
            float* o = Z2s + (size_t)i*96 + c4*4;
            o[0] = di*o0; o[1] = di*o1; o[2] = di*o2; o[3] = di*o3;
        }
    }
}

// ---------------------------------------------------------------------------
// k_propF1: R6-exact
// ---------------------------------------------------------------------------
__global__ __launch_bounds__(256) void k_propF1(
    const float* __restrict__ red, const float* __restrict__ dinv,
    unsigned short* __restrict__ Xb)
{
    for (int idx = blockIdx.x*256 + threadIdx.x; idx < 98400; idx += 192*256) {
        int r = idx / 96;
        __hip_bfloat16 hb = __float2bfloat16(dinv[r] * red[idx]);
        Xb[idx] = *(unsigned short*)&hb;
    }
}

// ---------------------------------------------------------------------------
// k_dec: R6-exact
// ---------------------------------------------------------------------------
__global__ __launch_bounds__(256) void k_dec(
    const unsigned short* __restrict__ Xb,
    const float* __restrict__ cW, const float* __restrict__ cB,
    const float* __restrict__ lW, const float* __restrict__ lB,
    const float* __restrict__ bW, const float* __restrict__ bB,
    float* __restrict__ out)
{
    int b = blockIdx.x, tid = threadIdx.x;
    int w = tid >> 6, lane = tid & 63;
    int n16 = lane & 15, kg = lane >> 4;

    const float *W, *Bv;
    int g0, kcw, ncols, div, ostride;
    size_t obase;
    if (b < 576) {                       // conv decoder
        int kb = b >> 1, mb = b & 1;
        W = cW; Bv = cB; g0 = 1 + mb*256; kcw = kb*128 + w*32; ncols = 36864;
        div = 576; obase = (size_t)mb*256*36864; ostride = 36864;
    } else if (b < 608) {                // lin decoder
        int kb = b - 576;
        W = lW; Bv = lB; g0 = 513; kcw = kb*128 + w*32; ncols = 4096;
        div = 64; obase = (size_t)18874368; ostride = 4096;
    } else {                             // bias decoder
        W = bW; Bv = bB; g0 = 769; kcw = w*32; ncols = 64;
        div = 0; obase = (size_t)19922944; ostride = 64;
    }
    if (kcw >= ncols) return;

    int kc_a = kcw + n16, kc_b = kcw + 16 + n16;
    int row_a = div ? kc_a + (kc_a/div)*div : kc_a;
    int row_b = div ? kc_b + (kc_b/div)*div : kc_b;
    const float* Wa = W + (size_t)row_a*96 + kg*8;
    const float* Wb = W + (size_t)row_b*96 + kg*8;
    bf16x8 ba0 = cvt8(Wa);
    bf16x8 ba1 = cvt8(Wa + 32);
    bf16x8 ba2 = cvt8(Wa + 64);
    bf16x8 bb0 = cvt8(Wb);
    bf16x8 bb1 = cvt8(Wb + 32);
    bf16x8 bb2 = cvt8(Wb + 64);
    float bva = Bv[row_a], bvb = Bv[row_b];

#pragma unroll 2
    for (int mt = 0; mt < 16; ++mt) {
        const unsigned short* Ar = Xb + (size_t)(g0 + mt*16 + n16)*96 + kg*8;
        bf16x8 a0 = *(const bf16x8*)(Ar);
        bf16x8 a1 = *(const bf16x8*)(Ar + 32);
        bf16x8 a2 = *(const bf16x8*)(Ar + 64);
        f32x4 acc0 = {0.f,0.f,0.f,0.f}, acc1 = {0.f,0.f,0.f,0.f};
        acc0 = MFMA16(a0, ba0, acc0);
        acc0 = MFMA16(a1, ba1, acc0);
        acc0 = MFMA16(a2, ba2, acc0);
        acc1 = MFMA16(a0, bb0, acc1);
        acc1 = MFMA16(a1, bb1, acc1);
        acc1 = MFMA16(a2, bb2, acc1);
#pragma unroll
        for (int r = 0; r < 4; ++r) {
            int node = mt*16 + kg*4 + r;
            out[obase + (size_t)node*ostride + kc_a] = acc0[r] + bva;
            out[obase + (size_t)node*ostride + kc_b] = acc1[r] + bvb;
        }
    }
}

// ---------------------------------------------------------------------------
extern "C" void kernel_launch(void* const* d_in, const int* in_sizes, int n_in,
                              void* d_out, int out_size, void* d_ws, size_t ws_size,
                              hipStream_t stream)
{
    const float* conv_w     = (const float*)d_in[0];
    const float* lin_w      = (const float*)d_in[1];
    const float* bias_w     = (const float*)d_in[2];
    const float* conv_enc_w = (const float*)d_in[3];
    const float* conv_enc_b = (const float*)d_in[4];
    const float* lin_enc_w  = (const float*)d_in[5];
    const float* lin_enc_b  = (const float*)d_in[6];
    const float* bias_enc_w = (const float*)d_in[7];
    const float* bias_enc_b = (const float*)d_in[8];
    const float* gcn_w1     = (const float*)d_in[9];
    const float* gcn_w2     = (const float*)d_in[10];
    const float* conv_dec_w = (const float*)d_in[11];
    const float* conv_dec_b = (const float*)d_in[12];
    const float* lin_dec_w  = (const float*)d_in[13];
    const float* lin_dec_b  = (const float*)d_in[14];
    const float* bias_dec_w = (const float*)d_in[15];
    const float* bias_dec_b = (const float*)d_in[16];
    const float* embed_tab  = (const float*)d_in[17];
    const int*   adj        = (const int*)d_in[18];
    const int*   prims      = (const int*)d_in[19];

    // workspace (floats): P 32*1024*32 | Z1s | Z2s | dinv | Xb(bf16) | red
    float* P    = (float*)d_ws;             // 1048576 f = 4 MB
    float* Z1s  = P + (size_t)32*1024*32;   // 98400 f
    float* Z2s  = Z1s + 1025*96;            // 98400 f
    float* dinv = Z2s + 1025*96;            // 1056 f
    unsigned short* Xb = (unsigned short*)(dinv + 1056);  // 98400 bf16
    float* red  = (float*)(Xb + (size_t)1025*96);         // 98400 f

    k_enc<<<352, 256, 0, stream>>>(conv_w, lin_w, bias_w,
                                   conv_enc_w, lin_enc_w, bias_enc_w,
                                   adj, P, dinv);
    k_z1<<<129, 256, 0, stream>>>(P, conv_enc_b, lin_enc_b, bias_enc_b,
                                  embed_tab, prims, gcn_w1, dinv, Z1s, red);
    k_propA<<<416, 256, 0, stream>>>(Z1s, adj, red);
    k_propF0<<<205, 256, 0, stream>>>(red, dinv, gcn_w2, Z2s, red);
    k_propA<<<416, 256, 0, stream>>>(Z2s, adj, red);
    k_propF1<<<192, 256, 0, stream>>>(red, dinv, Xb);
    k_dec<<<609, 256, 0, stream>>>(Xb, conv_dec_w, conv_dec_b,
                                   lin_dec_w, lin_dec_b,
                                   bias_dec_w, bias_dec_b,
                                   (float*)d_out);
}

// Round 8
// 305.556 us; speedup vs baseline: 1.0082x; 1.0082x over previous
//
#include <hip/hip_runtime.h>
#include <hip/hip_bf16.h>

// ---------------------------------------------------------------------------
// GHN (float32 I/O): encode (3 gathered GEMMs, bf16 MFMA, f32 acc)
//   -> 2-layer GCN -> decode (gathered GEMMs, MFMA) -> f32
// R8: k_enc reverted to R6 (fastest; 5 variants in 42-50us -> externally
// pinned, per pre-commitment). NEW: k_dec stores staged through LDS tiles
// ([16][132] dbuf) -> fully coalesced float4 row writes (was 4x scattered
// 64B segments per store instr). k_z1/k_propA/k_propF0/k_propF1: R6-exact.
// ---------------------------------------------------------------------------

typedef __attribute__((ext_vector_type(8))) __bf16 bf16x8;
typedef __attribute__((ext_vector_type(4))) float f32x4;

#define MFMA16(a,b,c) __builtin_amdgcn_mfma_f32_16x16x32_bf16((a),(b),(c),0,0,0)

__device__ __forceinline__ bf16x8 cvt8(const float* p) {
    float4 a = *(const float4*)p;
    float4 b = *(const float4*)(p + 4);
    bf16x8 r;
    r[0]=(__bf16)a.x; r[1]=(__bf16)a.y; r[2]=(__bf16)a.z; r[3]=(__bf16)a.w;
    r[4]=(__bf16)b.x; r[5]=(__bf16)b.y; r[6]=(__bf16)b.z; r[7]=(__bf16)b.w;
    return r;
}

// single-mtile direct tile (bias encoder)
template<int KSTEPS, int DIV>
__device__ __forceinline__ void enc_tile(const float* Ar,
                                         const float* B0,
                                         const float* B1,
                                         int kw, int kg, f32x4& acc0, f32x4& acc1)
{
#pragma unroll
    for (int s = 0; s < KSTEPS; ++s) {
        int k = kw + s*32 + kg*8;
        int col = DIV ? (k + (k/DIV)*DIV) : k;
        bf16x8 a  = cvt8(Ar + k);
        bf16x8 b0 = cvt8(B0 + col);
        bf16x8 b1 = cvt8(B1 + col);
        acc0 = MFMA16(a, b0, acc0);
        acc1 = MFMA16(a, b1, acc1);
    }
}

// 4-mtile tile: one B load pair feeds 4 A tiles (8 MFMA) per K-step
template<int KSTEPS, int DIV>
__device__ __forceinline__ void enc_tile4(const float* Abase, size_t AST,
                                          const float* B0, const float* B1,
                                          int kw, int n16, int kg,
                                          f32x4 (&acc0)[4], f32x4 (&acc1)[4])
{
#pragma unroll
    for (int s = 0; s < KSTEPS; ++s) {
        int k = kw + s*32 + kg*8;
        int col = k + (k/DIV)*DIV;
        bf16x8 b0 = cvt8(B0 + col);
        bf16x8 b1 = cvt8(B1 + col);
#pragma unroll
        for (int m = 0; m < 4; ++m) {
            bf16x8 a = cvt8(Abase + (size_t)(m*16 + n16)*AST + k);
            acc0[m] = MFMA16(a, b0, acc0[m]);
            acc1[m] = MFMA16(a, b1, acc1[m]);
        }
    }
}

// ---------------------------------------------------------------------------
// k_enc: R6-exact. conv 128 blocks (8 mg x 16 ks), lin 16, bias 16, dinv 64.
// ---------------------------------------------------------------------------
__global__ __launch_bounds__(256) void k_enc(
    const float* __restrict__ conv_w,
    const float* __restrict__ lin_w,
    const float* __restrict__ bias_w,
    const float* __restrict__ conv_enc_w,
    const float* __restrict__ lin_enc_w,
    const float* __restrict__ bias_enc_w,
    const int* __restrict__ adj,
    float* __restrict__ P, float* __restrict__ dinv)
{
    int b = blockIdx.x, tid = threadIdx.x;
    int w = tid >> 6, lane = tid & 63;
    int n16 = lane & 15, kg = lane >> 4;

    if (b >= 160) {  // ---- dinv rows (64 blocks)
        int wid = (b - 160)*4 + w;
        for (int r = wid; r < 1025; r += 256) {
            const int* row = adj + (size_t)r*1025;
            int s = 0;
#pragma unroll
            for (int i = 0; i <= 16; ++i) {
                int j = lane + i*64;
                if (j < 1025) s += row[j];
            }
#pragma unroll
            for (int off = 32; off; off >>= 1) s += __shfl_xor(s, off, 64);
            if (lane == 0) dinv[r] = 1.0f / sqrtf((float)s + 1.0f);
        }
        return;
    }

    __shared__ float R[4*4*512];   // 32 KB

    if (b < 144) {   // ---- conv (b<128) & lin (128<=b<144): 4-mtile path
        f32x4 acc0[4] = {{0,0,0,0},{0,0,0,0},{0,0,0,0},{0,0,0,0}};
        f32x4 acc1[4] = {{0,0,0,0},{0,0,0,0},{0,0,0,0},{0,0,0,0}};
        int slot, nodebase, mbase;
        if (b < 128) {            // conv: M=512, K=36864; mg=b>>4, ks=b&15
            int mg = b >> 4, ks = b & 15;
            slot = ks; nodebase = 0; mbase = mg*4;
            const float* B0 = conv_enc_w + (size_t)n16*147456;
            const float* B1 = conv_enc_w + (size_t)(16+n16)*147456;
            enc_tile4<18,576>(conv_w + (size_t)mbase*16*36864, 36864,
                              B0, B1, ks*2304 + w*576, n16, kg, acc0, acc1);
        } else {                  // lin: M=256, K=4096; 4 mg x 4 ks
            int bb = b - 128; int mg = bb >> 2, ks = bb & 3;
            slot = ks; nodebase = 512; mbase = mg*4;
            const float* B0 = lin_enc_w + (size_t)n16*16384;
            const float* B1 = lin_enc_w + (size_t)(16+n16)*16384;
            enc_tile4<8,64>(lin_w + (size_t)mbase*16*4096, 4096,
                            B0, B1, ks*1024 + w*256, n16, kg, acc0, acc1);
        }
#pragma unroll
        for (int m = 0; m < 4; ++m)
#pragma unroll
            for (int r = 0; r < 4; ++r) {
                R[((w*4 + m)*16 + kg*4 + r)*32 + n16]      = acc0[m][r];
                R[((w*4 + m)*16 + kg*4 + r)*32 + 16 + n16] = acc1[m][r];
            }
        __syncthreads();
        for (int e = tid; e < 2048; e += 256) {
            int m = e >> 9, wi = e & 511;
            float s = R[m*512 + wi]        + R[(4+m)*512 + wi]
                    + R[(8+m)*512 + wi]    + R[(12+m)*512 + wi];
            int nl = wi >> 5, h = wi & 31;
            int node = nodebase + (mbase + m)*16 + nl;
            P[((size_t)slot*1024 + node)*32 + h] = s;
        }
    } else {         // ---- bias (144<=b<160): single-mtile path
        int mtile = b - 144;
        f32x4 acc0 = {0,0,0,0}, acc1 = {0,0,0,0};
        if (w < 2) {
            const float* Ar = bias_w     + (size_t)(mtile*16 + n16)*64;
            const float* B0 = bias_enc_w + (size_t)n16*128;
            const float* B1 = bias_enc_w + (size_t)(16+n16)*128;
            enc_tile<1,0>(Ar, B0, B1, w*32, kg, acc0, acc1);
        }
#pragma unroll
        for (int r = 0; r < 4; ++r) {
            R[(w*16 + kg*4 + r)*32 + n16]      = acc0[r];
            R[(w*16 + kg*4 + r)*32 + 16 + n16] = acc1[r];
        }
        __syncthreads();
        for (int e = tid; e < 512; e += 256) {
            float s = R[e] + R[512+e] + R[1024+e] + R[1536+e];
            int nl = e >> 5, h = e & 31;
            int node = 768 + mtile*16 + nl;
            P[(size_t)node*32 + h] = s;          // slot 0
        }
    }
}

// ---------------------------------------------------------------------------
// k_z1: R6-exact (ns=16 conv slots; + red zeroing)
// ---------------------------------------------------------------------------
__global__ __launch_bounds__(256) void k_z1(
    const float* __restrict__ P,
    const float* __restrict__ conv_enc_b,
    const float* __restrict__ lin_enc_b,
    const float* __restrict__ bias_enc_b,
    const float* __restrict__ embed_tab,
    const int* __restrict__ prims,
    const float* __restrict__ gcn_w1,
    const float* __restrict__ dinv,
    float* __restrict__ Z1s,
    float* __restrict__ red)
{
    __shared__ float El[8*32], Ml[8*32];
    int tid = threadIdx.x;
    int i0 = blockIdx.x * 8;

    for (int idx = blockIdx.x*256 + tid; idx < 98400; idx += 129*256)
        red[idx] = 0.f;

    {
        int rl = tid >> 5, h = tid & 31;
        int i = i0 + rl;
        if (i < 1025) {
            float e, m;
            if (i == 0) { e = 1.0f; m = 1.0f; }
            else {
                int node = i - 1;
                int ns; float bias;
                if (node < 512)      { ns = 16; bias = conv_enc_b[h]; }
                else if (node < 768) { ns = 4;  bias = lin_enc_b[h];  }
                else                 { ns = 1;  bias = bias_enc_b[h]; }
                float s = bias;
                for (int sl = 0; sl < ns; ++sl)
                    s += P[((size_t)sl*1024 + node)*32 + h];
                e = s;
                m = embed_tab[prims[node]*32 + h];
            }
            El[rl*32+h] = e; Ml[rl*32+h] = m;
        }
    }
    __syncthreads();
    if (tid < 192) {
        int rl = tid / 24, c4 = tid % 24;
        int i = i0 + rl;
        if (i < 1025) {
            float a0=0,a1=0,a2=0,a3=0;
            for (int h = 0; h < 32; ++h) {
                float e = El[rl*32+h], m = Ml[rl*32+h];
                float4 wa = *(const float4*)(gcn_w1 + h*96 + c4*4);
                float4 wb = *(const float4*)(gcn_w1 + (h+32)*96 + c4*4);
                float4 wc = *(const float4*)(gcn_w1 + (h+64)*96 + c4*4);
                a0 += e*(wa.x+wb.x) + m*wc.x;
                a1 += e*(wa.y+wb.y) + m*wc.y;
                a2 += e*(wa.z+wb.z) + m*wc.z;
                a3 += e*(wa.w+wb.w) + m*wc.w;
            }
            float di = dinv[i];
            float* o = Z1s + (size_t)i*96 + c4*4;
            o[0] = di*a0; o[1] = di*a1; o[2] = di*a2; o[3] = di*a3;
        }
    }
}

// ---------------------------------------------------------------------------
// k_propA: R6-exact
// ---------------------------------------------------------------------------
__global__ __launch_bounds__(256) void k_propA(
    const float* __restrict__ Zs, const int* __restrict__ adj,
    float* __restrict__ red)
{
    __shared__ float adjf[20*132];
    int tid = threadIdx.x;
    int jc = blockIdx.x & 7, it = blockIdx.x >> 3;
    int i0 = it * 20;
    int j0 = jc * 128;
    int jlen = (jc == 7) ? 129 : 128;

    for (int idx = tid; idx < 20*132; idx += 256) {
        int row = idx / 132, c = idx % 132;
        int i = i0 + row, j = j0 + c;
        if (c < jlen && i < 1025)
            adjf[row*132 + c] = (float)adj[(size_t)i*1025 + j]
                                + (i == j ? 1.0f : 0.0f);
    }
    __syncthreads();

    if (tid < 240) {
        int c4 = tid % 24, ig = tid / 24;
        int rA = i0 + ig, rB = i0 + ig + 10;
        float accA[4] = {0,0,0,0}, accB[4] = {0,0,0,0};
        for (int jj = 0; jj < jlen; ++jj) {
            const float4 z = *(const float4*)(Zs + (size_t)(j0+jj)*96 + c4*4);
            float aA = adjf[ig*132 + jj];
            float aB = adjf[(ig+10)*132 + jj];
            accA[0] += aA*z.x; accA[1] += aA*z.y;
            accA[2] += aA*z.z; accA[3] += aA*z.w;
            accB[0] += aB*z.x; accB[1] += aB*z.y;
            accB[2] += aB*z.z; accB[3] += aB*z.w;
        }
        if (rA < 1025) {
            float* o = red + (size_t)rA*96 + c4*4;
            atomicAdd(o+0, accA[0]); atomicAdd(o+1, accA[1]);
            atomicAdd(o+2, accA[2]); atomicAdd(o+3, accA[3]);
        }
        if (rB < 1025) {
            float* o = red + (size_t)rB*96 + c4*4;
            atomicAdd(o+0, accB[0]); atomicAdd(o+1, accB[1]);
            atomicAdd(o+2, accB[2]); atomicAdd(o+3, accB[3]);
        }
    }
}

// ---------------------------------------------------------------------------
// k_propF0: R6-exact
// ---------------------------------------------------------------------------
__global__ __launch_bounds__(256) void k_propF0(
    const float* __restrict__ red, const float* __restrict__ dinv,
    const float* __restrict__ gcn_w2,
    float* __restrict__ Z2s, float* __restrict__ redz)
{
    __shared__ float redl[5*96];
    int tid = threadIdx.x;
    int i0 = blockIdx.x * 5;
    for (int idx = tid; idx < 5*96; idx += 256) {
        int r = idx / 96, c = idx % 96;
        int i = i0 + r;
        if (i < 1025) {
            redl[idx] = red[(size_t)i*96 + c];
            redz[(size_t)i*96 + c] = 0.f;
        }
    }
    __syncthreads();
    if (tid < 120) {
        int c4 = tid % 24, ig = tid / 24;
        int i = i0 + ig;
        if (i < 1025) {
            float di = dinv[i];
            float o0=0,o1=0,o2=0,o3=0;
            for (int c = 0; c < 96; ++c) {
                float hv = redl[ig*96 + c] * di; hv = hv > 0.f ? hv : 0.f;
                float4 w2 = *(const float4*)(gcn_w2 + c*96 + c4*4);
                o0 += hv*w2.x; o1 += hv*w2.y; o2 += hv*w2.z; o3 += hv*w2.w;
            }
            float* o = Z2s + (size_t)i*96 + c4*4;
            o[0] = di*o0; o[1] = di*o1; o[2] = di*o2; o[3] = di*o3;
        }
    }
}

// ---------------------------------------------------------------------------
// k_propF1: R6-exact
// ---------------------------------------------------------------------------
__global__ __launch_bounds__(256) void k_propF1(
    const float* __restrict__ red, const float* __restrict__ dinv,
    unsigned short* __restrict__ Xb)
{
    for (int idx = blockIdx.x*256 + threadIdx.x; idx < 98400; idx += 192*256) {
        int r = idx / 96;
        __hip_bfloat16 hb = __float2bfloat16(dinv[r] * red[idx]);
        Xb[idx] = *(unsigned short*)&hb;
    }
}

// ---------------------------------------------------------------------------
// k_dec: MFMA as before, but conv/lin stores staged through LDS tiles:
// per mt, block output is a dense 16-node x 128-col tile -> stage acc+bias
// into T[buf][16][132], sync, write float4 rows (1 KB contiguous per wave).
// Double-buffered -> one sync per mt. Bias decoder (b=608) keeps direct path.
// ---------------------------------------------------------------------------
__global__ __launch_bounds__(256) void k_dec(
    const unsigned short* __restrict__ Xb,
    const float* __restrict__ cW, const float* __restrict__ cB,
    const float* __restrict__ lW, const float* __restrict__ lB,
    const float* __restrict__ bW, const float* __restrict__ bB,
    float* __restrict__ out)
{
    __shared__ float T[2][16][132];
    int b = blockIdx.x, tid = threadIdx.x;
    int w = tid >> 6, lane = tid & 63;
    int n16 = lane & 15, kg = lane >> 4;

    if (b < 608) {   // ---- conv / lin decoders: LDS-staged coalesced stores
        const float *W, *Bv;
        int g0, kb, div, ostride;
        size_t obase;
        if (b < 576) {                   // conv: 288 kb x 2 node-halves
            int mb = b & 1; kb = b >> 1;
            W = cW; Bv = cB; g0 = 1 + mb*256; div = 576;
            obase = (size_t)mb*256*36864; ostride = 36864;
        } else {                         // lin: 32 kb
            kb = b - 576;
            W = lW; Bv = lB; g0 = 513; div = 64;
            obase = (size_t)18874368; ostride = 4096;
        }
        int colbase = kb*128;
        int kc_a = colbase + w*32 + n16, kc_b = kc_a + 16;
        int row_a = kc_a + (kc_a/div)*div;       // padded weight-row index
        int row_b = kc_b + (kc_b/div)*div;
        const float* Wa = W + (size_t)row_a*96 + kg*8;
        const float* Wb = W + (size_t)row_b*96 + kg*8;
        bf16x8 ba0 = cvt8(Wa);
        bf16x8 ba1 = cvt8(Wa + 32);
        bf16x8 ba2 = cvt8(Wa + 64);
        bf16x8 bb0 = cvt8(Wb);
        bf16x8 bb1 = cvt8(Wb + 32);
        bf16x8 bb2 = cvt8(Wb + 64);
        float bva = Bv[row_a], bvb = Bv[row_b];

#pragma unroll 2
        for (int mt = 0; mt < 16; ++mt) {
            const unsigned short* Ar = Xb + (size_t)(g0 + mt*16 + n16)*96 + kg*8;
            bf16x8 a0 = *(const bf16x8*)(Ar);
            bf16x8 a1 = *(const bf16x8*)(Ar + 32);
            bf16x8 a2 = *(const bf16x8*)(Ar + 64);
            f32x4 acc0 = {0.f,0.f,0.f,0.f}, acc1 = {0.f,0.f,0.f,0.f};
            acc0 = MFMA16(a0, ba0, acc0);
            acc0 = MFMA16(a1, ba1, acc0);
            acc0 = MFMA16(a2, ba2, acc0);
            acc1 = MFMA16(a0, bb0, acc1);
            acc1 = MFMA16(a1, bb1, acc1);
            acc1 = MFMA16(a2, bb2, acc1);
            int buf = mt & 1;
#pragma unroll
            for (int r = 0; r < 4; ++r) {
                T[buf][kg*4 + r][w*32 + n16]      = acc0[r] + bva;
                T[buf][kg*4 + r][w*32 + 16 + n16] = acc1[r] + bvb;
            }
            __syncthreads();
            // write 16 rows x 128 cols as float4 (2 per thread)
#pragma unroll
            for (int p = 0; p < 2; ++p) {
                int idx = tid + p*256;
                int row = idx >> 5, c4 = idx & 31;
                float4 v = *(const float4*)&T[buf][row][c4*4];
                *(float4*)(out + obase + (size_t)(mt*16 + row)*ostride
                           + colbase + c4*4) = v;
            }
        }
    } else {         // ---- bias decoder: direct stores (waves 2,3 idle)
        const float* W = bW; const float* Bv = bB;
        int g0 = 769, kcw = w*32;
        size_t obase = (size_t)19922944;
        if (kcw >= 64) return;
        int kc_a = kcw + n16, kc_b = kcw + 16 + n16;
        const float* Wa = W + (size_t)kc_a*96 + kg*8;
        const float* Wb = W + (size_t)kc_b*96 + kg*8;
        bf16x8 ba0 = cvt8(Wa);
        bf16x8 ba1 = cvt8(Wa + 32);
        bf16x8 ba2 = cvt8(Wa + 64);
        bf16x8 bb0 = cvt8(Wb);
        bf16x8 bb1 = cvt8(Wb + 32);
        bf16x8 bb2 = cvt8(Wb + 64);
        float bva = Bv[kc_a], bvb = Bv[kc_b];
#pragma unroll 2
        for (int mt = 0; mt < 16; ++mt) {
            const unsigned short* Ar = Xb + (size_t)(g0 + mt*16 + n16)*96 + kg*8;
            bf16x8 a0 = *(const bf16x8*)(Ar);
            bf16x8 a1 = *(const bf16x8*)(Ar + 32);
            bf16x8 a2 = *(const bf16x8*)(Ar + 64);
            f32x4 acc0 = {0.f,0.f,0.f,0.f}, acc1 = {0.f,0.f,0.f,0.f};
            acc0 = MFMA16(a0, ba0, acc0);
            acc0 = MFMA16(a1, ba1, acc0);
            acc0 = MFMA16(a2, ba2, acc0);
            acc1 = MFMA16(a0, bb0, acc1);
            acc1 = MFMA16(a1, bb1, acc1);
            acc1 = MFMA16(a2, bb2, acc1);
#pragma unroll
            for (int r = 0; r < 4; ++r) {
                int node = mt*16 + kg*4 + r;
                out[obase + (size_t)node*64 + kc_a] = acc0[r] + bva;
                out[obase + (size_t)node*64 + kc_b] = acc1[r] + bvb;
            }
        }
    }
}

// ---------------------------------------------------------------------------
extern "C" void kernel_launch(void* const* d_in, const int* in_sizes, int n_in,
                              void* d_out, int out_size, void* d_ws, size_t ws_size,
                              hipStream_t stream)
{
    const float* conv_w     = (const float*)d_in[0];
    const float* lin_w      = (const float*)d_in[1];
    const float* bias_w     = (const float*)d_in[2];
    const float* conv_enc_w = (const float*)d_in[3];
    const float* conv_enc_b = (const float*)d_in[4];
    const float* lin_enc_w  = (const float*)d_in[5];
    const float* lin_enc_b  = (const float*)d_in[6];
    const float* bias_enc_w = (const float*)d_in[7];
    const float* bias_enc_b = (const float*)d_in[8];
    const float* gcn_w1     = (const float*)d_in[9];
    const float* gcn_w2     = (const float*)d_in[10];
    const float* conv_dec_w = (const float*)d_in[11];
    const float* conv_dec_b = (const float*)d_in[12];
    const float* lin_dec_w  = (const float*)d_in[13];
    const float* lin_dec_b  = (const float*)d_in[14];
    const float* bias_dec_w = (const float*)d_in[15];
    const float* bias_dec_b = (const float*)d_in[16];
    const float* embed_tab  = (const float*)d_in[17];
    const int*   adj        = (const int*)d_in[18];
    const int*   prims      = (const int*)d_in[19];

    // workspace (floats): P 16*1024*32 | Z1s | Z2s | dinv | Xb(bf16) | red
    float* P    = (float*)d_ws;             // 524288 f = 2 MB
    float* Z1s  = P + (size_t)16*1024*32;   // 98400 f
    float* Z2s  = Z1s + 1025*96;            // 98400 f
    float* dinv = Z2s + 1025*96;            // 1056 f
    unsigned short* Xb = (unsigned short*)(dinv + 1056);  // 98400 bf16
    float* red  = (float*)(Xb + (size_t)1025*96);         // 98400 f

    k_enc<<<224, 256, 0, stream>>>(conv_w, lin_w, bias_w,
                                   conv_enc_w, lin_enc_w, bias_enc_w,
                                   adj, P, dinv);
    k_z1<<<129, 256, 0, stream>>>(P, conv_enc_b, lin_enc_b, bias_enc_b,
                                  embed_tab, prims, gcn_w1, dinv, Z1s, red);
    k_propA<<<416, 256, 0, stream>>>(Z1s, adj, red);
    k_propF0<<<205, 256, 0, stream>>>(red, dinv, gcn_w2, Z2s, red);
    k_propA<<<416, 256, 0, stream>>>(Z2s, adj, red);
    k_propF1<<<192, 256, 0, stream>>>(red, dinv, Xb);
    k_dec<<<609, 256, 0, stream>>>(Xb, conv_dec_w, conv_dec_b,
                                   lin_dec_w, lin_dec_b,
                                   bias_dec_w, bias_dec_b,
                                   (float*)d_out);
}

// Round 9
// 303.508 us; speedup vs baseline: 1.0150x; 1.0067x over previous
//
#include <hip/hip_runtime.h>
#include <hip/hip_bf16.h>
#include <hip/hip_cooperative_groups.h>

namespace cg = cooperative_groups;

// ---------------------------------------------------------------------------
// GHN (float32 I/O): encode -> 2-layer GCN -> decode.
// R9: middle section (z1, propA, propF0, propA, propF1) fused into ONE
// cooperative kernel k_mid (416 blocks, 4 grid.sync) -- deletes 4 kernel
// boundaries without touching the big phases' concurrency (R2's mistake).
// k_enc: R6-exact (pinned ~43us). k_dec: R5-exact direct stores (staging
// was neutral-to-negative in R8). Fallback: separate launches.
// ---------------------------------------------------------------------------

typedef __attribute__((ext_vector_type(8))) __bf16 bf16x8;
typedef __attribute__((ext_vector_type(4))) float f32x4;

#define MFMA16(a,b,c) __builtin_amdgcn_mfma_f32_16x16x32_bf16((a),(b),(c),0,0,0)

__device__ __forceinline__ bf16x8 cvt8(const float* p) {
    float4 a = *(const float4*)p;
    float4 b = *(const float4*)(p + 4);
    bf16x8 r;
    r[0]=(__bf16)a.x; r[1]=(__bf16)a.y; r[2]=(__bf16)a.z; r[3]=(__bf16)a.w;
    r[4]=(__bf16)b.x; r[5]=(__bf16)b.y; r[6]=(__bf16)b.z; r[7]=(__bf16)b.w;
    return r;
}

template<int KSTEPS, int DIV>
__device__ __forceinline__ void enc_tile(const float* Ar,
                                         const float* B0,
                                         const float* B1,
                                         int kw, int kg, f32x4& acc0, f32x4& acc1)
{
#pragma unroll
    for (int s = 0; s < KSTEPS; ++s) {
        int k = kw + s*32 + kg*8;
        int col = DIV ? (k + (k/DIV)*DIV) : k;
        bf16x8 a  = cvt8(Ar + k);
        bf16x8 b0 = cvt8(B0 + col);
        bf16x8 b1 = cvt8(B1 + col);
        acc0 = MFMA16(a, b0, acc0);
        acc1 = MFMA16(a, b1, acc1);
    }
}

template<int KSTEPS, int DIV>
__device__ __forceinline__ void enc_tile4(const float* Abase, size_t AST,
                                          const float* B0, const float* B1,
                                          int kw, int n16, int kg,
                                          f32x4 (&acc0)[4], f32x4 (&acc1)[4])
{
#pragma unroll
    for (int s = 0; s < KSTEPS; ++s) {
        int k = kw + s*32 + kg*8;
        int col = k + (k/DIV)*DIV;
        bf16x8 b0 = cvt8(B0 + col);
        bf16x8 b1 = cvt8(B1 + col);
#pragma unroll
        for (int m = 0; m < 4; ++m) {
            bf16x8 a = cvt8(Abase + (size_t)(m*16 + n16)*AST + k);
            acc0[m] = MFMA16(a, b0, acc0[m]);
            acc1[m] = MFMA16(a, b1, acc1[m]);
        }
    }
}

// ---------------------------------------------------------------------------
// k_enc: R6-exact. conv 128 blocks (8 mg x 16 ks), lin 16, bias 16, dinv 64.
// ---------------------------------------------------------------------------
__global__ __launch_bounds__(256) void k_enc(
    const float* __restrict__ conv_w,
    const float* __restrict__ lin_w,
    const float* __restrict__ bias_w,
    const float* __restrict__ conv_enc_w,
    const float* __restrict__ lin_enc_w,
    const float* __restrict__ bias_enc_w,
    const int* __restrict__ adj,
    float* __restrict__ P, float* __restrict__ dinv)
{
    int b = blockIdx.x, tid = threadIdx.x;
    int w = tid >> 6, lane = tid & 63;
    int n16 = lane & 15, kg = lane >> 4;

    if (b >= 160) {  // ---- dinv rows (64 blocks)
        int wid = (b - 160)*4 + w;
        for (int r = wid; r < 1025; r += 256) {
            const int* row = adj + (size_t)r*1025;
            int s = 0;
#pragma unroll
            for (int i = 0; i <= 16; ++i) {
                int j = lane + i*64;
                if (j < 1025) s += row[j];
            }
#pragma unroll
            for (int off = 32; off; off >>= 1) s += __shfl_xor(s, off, 64);
            if (lane == 0) dinv[r] = 1.0f / sqrtf((float)s + 1.0f);
        }
        return;
    }

    __shared__ float R[4*4*512];   // 32 KB

    if (b < 144) {   // ---- conv (b<128) & lin (128<=b<144): 4-mtile path
        f32x4 acc0[4] = {{0,0,0,0},{0,0,0,0},{0,0,0,0},{0,0,0,0}};
        f32x4 acc1[4] = {{0,0,0,0},{0,0,0,0},{0,0,0,0},{0,0,0,0}};
        int slot, nodebase, mbase;
        if (b < 128) {            // conv: M=512, K=36864; mg=b>>4, ks=b&15
            int mg = b >> 4, ks = b & 15;
            slot = ks; nodebase = 0; mbase = mg*4;
            const float* B0 = conv_enc_w + (size_t)n16*147456;
            const float* B1 = conv_enc_w + (size_t)(16+n16)*147456;
            enc_tile4<18,576>(conv_w + (size_t)mbase*16*36864, 36864,
                              B0, B1, ks*2304 + w*576, n16, kg, acc0, acc1);
        } else {                  // lin: M=256, K=4096; 4 mg x 4 ks
            int bb = b - 128; int mg = bb >> 2, ks = bb & 3;
            slot = ks; nodebase = 512; mbase = mg*4;
            const float* B0 = lin_enc_w + (size_t)n16*16384;
            const float* B1 = lin_enc_w + (size_t)(16+n16)*16384;
            enc_tile4<8,64>(lin_w + (size_t)mbase*16*4096, 4096,
                            B0, B1, ks*1024 + w*256, n16, kg, acc0, acc1);
        }
#pragma unroll
        for (int m = 0; m < 4; ++m)
#pragma unroll
            for (int r = 0; r < 4; ++r) {
                R[((w*4 + m)*16 + kg*4 + r)*32 + n16]      = acc0[m][r];
                R[((w*4 + m)*16 + kg*4 + r)*32 + 16 + n16] = acc1[m][r];
            }
        __syncthreads();
        for (int e = tid; e < 2048; e += 256) {
            int m = e >> 9, wi = e & 511;
            float s = R[m*512 + wi]        + R[(4+m)*512 + wi]
                    + R[(8+m)*512 + wi]    + R[(12+m)*512 + wi];
            int nl = wi >> 5, h = wi & 31;
            int node = nodebase + (mbase + m)*16 + nl;
            P[((size_t)slot*1024 + node)*32 + h] = s;
        }
    } else {         // ---- bias (144<=b<160): single-mtile path
        int mtile = b - 144;
        f32x4 acc0 = {0,0,0,0}, acc1 = {0,0,0,0};
        if (w < 2) {
            const float* Ar = bias_w     + (size_t)(mtile*16 + n16)*64;
            const float* B0 = bias_enc_w + (size_t)n16*128;
            const float* B1 = bias_enc_w + (size_t)(16+n16)*128;
            enc_tile<1,0>(Ar, B0, B1, w*32, kg, acc0, acc1);
        }
#pragma unroll
        for (int r = 0; r < 4; ++r) {
            R[(w*16 + kg*4 + r)*32 + n16]      = acc0[r];
            R[(w*16 + kg*4 + r)*32 + 16 + n16] = acc1[r];
        }
        __syncthreads();
        for (int e = tid; e < 512; e += 256) {
            float s = R[e] + R[512+e] + R[1024+e] + R[1536+e];
            int nl = e >> 5, h = e & 31;
            int node = 768 + mtile*16 + nl;
            P[(size_t)node*32 + h] = s;          // slot 0
        }
    }
}

// ---------------------------------------------------------------------------
// Shared phase bodies (used by both coop k_mid and fallback kernels)
// ---------------------------------------------------------------------------
struct MidP {
    const float *P, *conv_enc_b, *lin_enc_b, *bias_enc_b;
    const float *embed_tab, *gcn_w1, *gcn_w2, *dinv;
    const int *prims, *adj;
    float *Z1s, *Z2s, *red;
    unsigned short *Xb;
};

__device__ __forceinline__ void z1_unit(const MidP& p, float* smem,
                                        int blk, int tid)
{
    float* El = smem;          // 256 f
    float* Ml = smem + 256;    // 256 f
    int i0 = blk * 8;
    {
        int rl = tid >> 5, h = tid & 31;
        int i = i0 + rl;
        if (i < 1025) {
            float e, m;
            if (i == 0) { e = 1.0f; m = 1.0f; }
            else {
                int node = i - 1;
                int ns; float bias;
                if (node < 512)      { ns = 16; bias = p.conv_enc_b[h]; }
                else if (node < 768) { ns = 4;  bias = p.lin_enc_b[h];  }
                else                 { ns = 1;  bias = p.bias_enc_b[h]; }
                float s = bias;
                for (int sl = 0; sl < ns; ++sl)
                    s += p.P[((size_t)sl*1024 + node)*32 + h];
                e = s;
                m = p.embed_tab[p.prims[node]*32 + h];
            }
            El[rl*32+h] = e; Ml[rl*32+h] = m;
        }
    }
    __syncthreads();
    if (tid < 192) {
        int rl = tid / 24, c4 = tid % 24;
        int i = i0 + rl;
        if (i < 1025) {
            float a0=0,a1=0,a2=0,a3=0;
            for (int h = 0; h < 32; ++h) {
                float e = El[rl*32+h], m = Ml[rl*32+h];
                float4 wa = *(const float4*)(p.gcn_w1 + h*96 + c4*4);
                float4 wb = *(const float4*)(p.gcn_w1 + (h+32)*96 + c4*4);
                float4 wc = *(const float4*)(p.gcn_w1 + (h+64)*96 + c4*4);
                a0 += e*(wa.x+wb.x) + m*wc.x;
                a1 += e*(wa.y+wb.y) + m*wc.y;
                a2 += e*(wa.z+wb.z) + m*wc.z;
                a3 += e*(wa.w+wb.w) + m*wc.w;
            }
            float di = p.dinv[i];
            float* o = p.Z1s + (size_t)i*96 + c4*4;
            o[0] = di*a0; o[1] = di*a1; o[2] = di*a2; o[3] = di*a3;
        }
    }
    __syncthreads();   // LDS WAR
}

__device__ __forceinline__ void propA_unit(const MidP& p, const float* Zs,
                                           float* adjf, int blk, int tid)
{
    int jc = blk & 7, it = blk >> 3;
    int i0 = it * 20;
    int j0 = jc * 128;
    int jlen = (jc == 7) ? 129 : 128;

    for (int idx = tid; idx < 20*132; idx += 256) {
        int row = idx / 132, c = idx % 132;
        int i = i0 + row, j = j0 + c;
        if (c < jlen && i < 1025)
            adjf[row*132 + c] = (float)p.adj[(size_t)i*1025 + j]
                                + (i == j ? 1.0f : 0.0f);
    }
    __syncthreads();

    if (tid < 240) {
        int c4 = tid % 24, ig = tid / 24;
        int rA = i0 + ig, rB = i0 + ig + 10;
        float accA[4] = {0,0,0,0}, accB[4] = {0,0,0,0};
        for (int jj = 0; jj < jlen; ++jj) {
            const float4 z = *(const float4*)(Zs + (size_t)(j0+jj)*96 + c4*4);
            float aA = adjf[ig*132 + jj];
            float aB = adjf[(ig+10)*132 + jj];
            accA[0] += aA*z.x; accA[1] += aA*z.y;
            accA[2] += aA*z.z; accA[3] += aA*z.w;
            accB[0] += aB*z.x; accB[1] += aB*z.y;
            accB[2] += aB*z.z; accB[3] += aB*z.w;
        }
        if (rA < 1025) {
            float* o = p.red + (size_t)rA*96 + c4*4;
            atomicAdd(o+0, accA[0]); atomicAdd(o+1, accA[1]);
            atomicAdd(o+2, accA[2]); atomicAdd(o+3, accA[3]);
        }
        if (rB < 1025) {
            float* o = p.red + (size_t)rB*96 + c4*4;
            atomicAdd(o+0, accB[0]); atomicAdd(o+1, accB[1]);
            atomicAdd(o+2, accB[2]); atomicAdd(o+3, accB[3]);
        }
    }
    __syncthreads();   // LDS WAR
}

__device__ __forceinline__ void propF0_unit(const MidP& p, float* redl,
                                            int blk, int tid)
{
    int i0 = blk * 5;
    for (int idx = tid; idx < 5*96; idx += 256) {
        int r = idx / 96, c = idx % 96;
        int i = i0 + r;
        if (i < 1025) {
            redl[idx] = p.red[(size_t)i*96 + c];
            p.red[(size_t)i*96 + c] = 0.f;    // ready for phase-2 atomics
        }
    }
    __syncthreads();
    if (tid < 120) {
        int c4 = tid % 24, ig = tid / 24;
        int i = i0 + ig;
        if (i < 1025) {
            float di = p.dinv[i];
            float o0=0,o1=0,o2=0,o3=0;
            for (int c = 0; c < 96; ++c) {
                float hv = redl[ig*96 + c] * di; hv = hv > 0.f ? hv : 0.f;
                float4 w2 = *(const float4*)(p.gcn_w2 + c*96 + c4*4);
                o0 += hv*w2.x; o1 += hv*w2.y; o2 += hv*w2.z; o3 += hv*w2.w;
            }
            float* o = p.Z2s + (size_t)i*96 + c4*4;
            o[0] = di*o0; o[1] = di*o1; o[2] = di*o2; o[3] = di*o3;
        }
    }
    __syncthreads();   // LDS WAR
}

// ---------------------------------------------------------------------------
// k_mid: cooperative fusion of z1 -> propA(Z1s) -> propF0 -> propA(Z2s)
// -> propF1, with grid.sync() between phases (replaces 4 kernel boundaries).
// ---------------------------------------------------------------------------
__global__ __launch_bounds__(256) void k_mid(MidP p)
{
    __shared__ float smem[20*132];    // 10.56 KB, aliased per phase
    const int tid = threadIdx.x;
    cg::grid_group grid = cg::this_grid();

    // phase 1: zero red + z1
    for (int idx = blockIdx.x*256 + tid; idx < 98400; idx += gridDim.x*256)
        p.red[idx] = 0.f;
    for (int blk = blockIdx.x; blk < 129; blk += gridDim.x)
        z1_unit(p, smem, blk, tid);
    grid.sync();

    // phase 2: propA on Z1s
    for (int blk = blockIdx.x; blk < 416; blk += gridDim.x)
        propA_unit(p, p.Z1s, smem, blk, tid);
    grid.sync();

    // phase 3: propF0 (Z2s = dinv*relu(dinv*red)@W2; red re-zeroed)
    for (int blk = blockIdx.x; blk < 205; blk += gridDim.x)
        propF0_unit(p, smem, blk, tid);
    grid.sync();

    // phase 4: propA on Z2s
    for (int blk = blockIdx.x; blk < 416; blk += gridDim.x)
        propA_unit(p, p.Z2s, smem, blk, tid);
    grid.sync();

    // phase 5: propF1 (Xb = bf16(dinv*red))
    for (int idx = blockIdx.x*256 + tid; idx < 98400; idx += gridDim.x*256) {
        int r = idx / 96;
        __hip_bfloat16 hb = __float2bfloat16(p.dinv[r] * p.red[idx]);
        p.Xb[idx] = *(unsigned short*)&hb;
    }
}

// ---------------------------------------------------------------------------
// Fallback separate kernels (R6-exact semantics)
// ---------------------------------------------------------------------------
__global__ __launch_bounds__(256) void k_z1f(MidP p)
{
    __shared__ float smem[512];
    int tid = threadIdx.x;
    for (int idx = blockIdx.x*256 + tid; idx < 98400; idx += 129*256)
        p.red[idx] = 0.f;
    z1_unit(p, smem, blockIdx.x, tid);
}
__global__ __launch_bounds__(256) void k_propAf(MidP p, int phase)
{
    __shared__ float smem[20*132];
    propA_unit(p, phase == 0 ? p.Z1s : p.Z2s, smem, blockIdx.x, threadIdx.x);
}
__global__ __launch_bounds__(256) void k_propF0f(MidP p)
{
    __shared__ float smem[5*96];
    propF0_unit(p, smem, blockIdx.x, threadIdx.x);
}
__global__ __launch_bounds__(256) void k_propF1f(MidP p)
{
    for (int idx = blockIdx.x*256 + threadIdx.x; idx < 98400; idx += 192*256) {
        int r = idx / 96;
        __hip_bfloat16 hb = __float2bfloat16(p.dinv[r] * p.red[idx]);
        p.Xb[idx] = *(unsigned short*)&hb;
    }
}

// ---------------------------------------------------------------------------
// k_dec: R5-exact (direct stores; staging was neutral-negative in R8)
// ---------------------------------------------------------------------------
__global__ __launch_bounds__(256) void k_dec(
    const unsigned short* __restrict__ Xb,
    const float* __restrict__ cW, const float* __restrict__ cB,
    const float* __restrict__ lW, const float* __restrict__ lB,
    const float* __restrict__ bW, const float* __restrict__ bB,
    float* __restrict__ out)
{
    int b = blockIdx.x, tid = threadIdx.x;
    int w = tid >> 6, lane = tid & 63;
    int n16 = lane & 15, kg = lane >> 4;

    const float *W, *Bv;
    int g0, kcw, ncols, div, ostride;
    size_t obase;
    if (b < 576) {                       // conv decoder
        int kb = b >> 1, mb = b & 1;
        W = cW; Bv = cB; g0 = 1 + mb*256; kcw = kb*128 + w*32; ncols = 36864;
        div = 576; obase = (size_t)mb*256*36864; ostride = 36864;
    } else if (b < 608) {                // lin decoder
        int kb = b - 576;
        W = lW; Bv = lB; g0 = 513; kcw = kb*128 + w*32; ncols = 4096;
        div = 64; obase = (size_t)18874368; ostride = 4096;
    } else {                             // bias decoder
        W = bW; Bv = bB; g0 = 769; kcw = w*32; ncols = 64;
        div = 0; obase = (size_t)19922944; ostride = 64;
    }
    if (kcw >= ncols) return;

    int kc_a = kcw + n16, kc_b = kcw + 16 + n16;
    int row_a = div ? kc_a + (kc_a/div)*div : kc_a;
    int row_b = div ? kc_b + (kc_b/div)*div : kc_b;
    const float* Wa = W + (size_t)row_a*96 + kg*8;
    const float* Wb = W + (size_t)row_b*96 + kg*8;
    bf16x8 ba0 = cvt8(Wa);
    bf16x8 ba1 = cvt8(Wa + 32);
    bf16x8 ba2 = cvt8(Wa + 64);
    bf16x8 bb0 = cvt8(Wb);
    bf16x8 bb1 = cvt8(Wb + 32);
    bf16x8 bb2 = cvt8(Wb + 64);
    float bva = Bv[row_a], bvb = Bv[row_b];

#pragma unroll 2
    for (int mt = 0; mt < 16; ++mt) {
        const unsigned short* Ar = Xb + (size_t)(g0 + mt*16 + n16)*96 + kg*8;
        bf16x8 a0 = *(const bf16x8*)(Ar);
        bf16x8 a1 = *(const bf16x8*)(Ar + 32);
        bf16x8 a2 = *(const bf16x8*)(Ar + 64);
        f32x4 acc0 = {0.f,0.f,0.f,0.f}, acc1 = {0.f,0.f,0.f,0.f};
        acc0 = MFMA16(a0, ba0, acc0);
        acc0 = MFMA16(a1, ba1, acc0);
        acc0 = MFMA16(a2, ba2, acc0);
        acc1 = MFMA16(a0, bb0, acc1);
        acc1 = MFMA16(a1, bb1, acc1);
        acc1 = MFMA16(a2, bb2, acc1);
#pragma unroll
        for (int r = 0; r < 4; ++r) {
            int node = mt*16 + kg*4 + r;
            out[obase + (size_t)node*ostride + kc_a] = acc0[r] + bva;
            out[obase + (size_t)node*ostride + kc_b] = acc1[r] + bvb;
        }
    }
}

// ---------------------------------------------------------------------------
extern "C" void kernel_launch(void* const* d_in, const int* in_sizes, int n_in,
                              void* d_out, int out_size, void* d_ws, size_t ws_size,
                              hipStream_t stream)
{
    const float* conv_w     = (const float*)d_in[0];
    const float* lin_w      = (const float*)d_in[1];
    const float* bias_w     = (const float*)d_in[2];
    const float* conv_enc_w = (const float*)d_in[3];
    const float* conv_enc_b = (const float*)d_in[4];
    const float* lin_enc_w  = (const float*)d_in[5];
    const float* lin_enc_b  = (const float*)d_in[6];
    const float* bias_enc_w = (const float*)d_in[7];
    const float* bias_enc_b = (const float*)d_in[8];
    const float* gcn_w1     = (const float*)d_in[9];
    const float* gcn_w2     = (const float*)d_in[10];
    const float* conv_dec_w = (const float*)d_in[11];
    const float* conv_dec_b = (const float*)d_in[12];
    const float* lin_dec_w  = (const float*)d_in[13];
    const float* lin_dec_b  = (const float*)d_in[14];
    const float* bias_dec_w = (const float*)d_in[15];
    const float* bias_dec_b = (const float*)d_in[16];
    const float* embed_tab  = (const float*)d_in[17];
    const int*   adj        = (const int*)d_in[18];
    const int*   prims      = (const int*)d_in[19];

    // workspace (floats): P 16*1024*32 | Z1s | Z2s | dinv | Xb(bf16) | red
    float* P    = (float*)d_ws;             // 524288 f = 2 MB
    float* Z1s  = P + (size_t)16*1024*32;   // 98400 f
    float* Z2s  = Z1s + 1025*96;            // 98400 f
    float* dinv = Z2s + 1025*96;            // 1056 f
    unsigned short* Xb = (unsigned short*)(dinv + 1056);  // 98400 bf16
    float* red  = (float*)(Xb + (size_t)1025*96);         // 98400 f

    MidP mp;
    mp.P = P; mp.conv_enc_b = conv_enc_b; mp.lin_enc_b = lin_enc_b;
    mp.bias_enc_b = bias_enc_b; mp.embed_tab = embed_tab;
    mp.gcn_w1 = gcn_w1; mp.gcn_w2 = gcn_w2; mp.dinv = dinv;
    mp.prims = prims; mp.adj = adj;
    mp.Z1s = Z1s; mp.Z2s = Z2s; mp.red = red; mp.Xb = Xb;

    k_enc<<<224, 256, 0, stream>>>(conv_w, lin_w, bias_w,
                                   conv_enc_w, lin_enc_w, bias_enc_w,
                                   adj, P, dinv);

    // ---- middle section: cooperative fusion (fallback: separate launches)
    static int coop_state = 0;   // 0=unknown, 1=coop ok, -1=fallback
    if (coop_state == 0) {
        int nb = 0;
        hipError_t e = hipOccupancyMaxActiveBlocksPerMultiprocessor(
            &nb, k_mid, 256, 0);
        coop_state = (e == hipSuccess && nb*256 >= 416) ? 1 : -1;
    }
    bool done = false;
    if (coop_state == 1) {
        void* args[] = { (void*)&mp };
        hipError_t e = hipLaunchCooperativeKernel(
            (void*)k_mid, dim3(416), dim3(256), args, 0, stream);
        if (e == hipSuccess) done = true;
        else { (void)hipGetLastError(); coop_state = -1; }
    }
    if (!done) {
        k_z1f<<<129, 256, 0, stream>>>(mp);
        k_propAf<<<416, 256, 0, stream>>>(mp, 0);
        k_propF0f<<<205, 256, 0, stream>>>(mp);
        k_propAf<<<416, 256, 0, stream>>>(mp, 1);
        k_propF1f<<<192, 256, 0, stream>>>(mp);
    }

    k_dec<<<609, 256, 0, stream>>>(Xb, conv_dec_w, conv_dec_b,
                                   lin_dec_w, lin_dec_b,
                                   bias_dec_w, bias_dec_b,
                                   (float*)d_out);
}

// Round 10
// 302.073 us; speedup vs baseline: 1.0199x; 1.0048x over previous
//
#include <hip/hip_runtime.h>
#include <hip/hip_bf16.h>

// ---------------------------------------------------------------------------
// GHN (float32 I/O): encode (3 gathered GEMMs, bf16 MFMA, f32 acc)
//   -> 2-layer GCN -> decode (gathered GEMMs, MFMA) -> f32
// R10: revert to the R6 champion (299.3us). R9's cooperative k_mid measured
// 222-227us in direct-launch rocprof passes (grid.sync spin; HBM 1.7%,
// VALU 2.5%) and only avoided regressing the timed run because graph capture
// rejected the coop launch and took the fallback. Removed.
// Config: k_enc R6 (4-mtile B-reuse, 224 blocks), mid = 5 separate kernels
// (z1 -> propA -> propF0 -> propA -> propF1, global-dependency chain),
// k_dec R5 direct stores (staging neutral in R8).
// ---------------------------------------------------------------------------

typedef __attribute__((ext_vector_type(8))) __bf16 bf16x8;
typedef __attribute__((ext_vector_type(4))) float f32x4;

#define MFMA16(a,b,c) __builtin_amdgcn_mfma_f32_16x16x32_bf16((a),(b),(c),0,0,0)

__device__ __forceinline__ bf16x8 cvt8(const float* p) {
    float4 a = *(const float4*)p;
    float4 b = *(const float4*)(p + 4);
    bf16x8 r;
    r[0]=(__bf16)a.x; r[1]=(__bf16)a.y; r[2]=(__bf16)a.z; r[3]=(__bf16)a.w;
    r[4]=(__bf16)b.x; r[5]=(__bf16)b.y; r[6]=(__bf16)b.z; r[7]=(__bf16)b.w;
    return r;
}

// single-mtile direct tile (bias encoder)
template<int KSTEPS, int DIV>
__device__ __forceinline__ void enc_tile(const float* Ar,
                                         const float* B0,
                                         const float* B1,
                                         int kw, int kg, f32x4& acc0, f32x4& acc1)
{
#pragma unroll
    for (int s = 0; s < KSTEPS; ++s) {
        int k = kw + s*32 + kg*8;
        int col = DIV ? (k + (k/DIV)*DIV) : k;
        bf16x8 a  = cvt8(Ar + k);
        bf16x8 b0 = cvt8(B0 + col);
        bf16x8 b1 = cvt8(B1 + col);
        acc0 = MFMA16(a, b0, acc0);
        acc1 = MFMA16(a, b1, acc1);
    }
}

// 4-mtile tile: one B load pair feeds 4 A tiles (8 MFMA) per K-step
template<int KSTEPS, int DIV>
__device__ __forceinline__ void enc_tile4(const float* Abase, size_t AST,
                                          const float* B0, const float* B1,
                                          int kw, int n16, int kg,
                                          f32x4 (&acc0)[4], f32x4 (&acc1)[4])
{
#pragma unroll
    for (int s = 0; s < KSTEPS; ++s) {
        int k = kw + s*32 + kg*8;
        int col = k + (k/DIV)*DIV;
        bf16x8 b0 = cvt8(B0 + col);
        bf16x8 b1 = cvt8(B1 + col);
#pragma unroll
        for (int m = 0; m < 4; ++m) {
            bf16x8 a = cvt8(Abase + (size_t)(m*16 + n16)*AST + k);
            acc0[m] = MFMA16(a, b0, acc0[m]);
            acc1[m] = MFMA16(a, b1, acc1[m]);
        }
    }
}

// ---------------------------------------------------------------------------
// k_enc: R6-exact. conv 128 blocks (8 mg x 16 ks), lin 16, bias 16, dinv 64.
// ---------------------------------------------------------------------------
__global__ __launch_bounds__(256) void k_enc(
    const float* __restrict__ conv_w,
    const float* __restrict__ lin_w,
    const float* __restrict__ bias_w,
    const float* __restrict__ conv_enc_w,
    const float* __restrict__ lin_enc_w,
    const float* __restrict__ bias_enc_w,
    const int* __restrict__ adj,
    float* __restrict__ P, float* __restrict__ dinv)
{
    int b = blockIdx.x, tid = threadIdx.x;
    int w = tid >> 6, lane = tid & 63;
    int n16 = lane & 15, kg = lane >> 4;

    if (b >= 160) {  // ---- dinv rows (64 blocks)
        int wid = (b - 160)*4 + w;
        for (int r = wid; r < 1025; r += 256) {
            const int* row = adj + (size_t)r*1025;
            int s = 0;
#pragma unroll
            for (int i = 0; i <= 16; ++i) {
                int j = lane + i*64;
                if (j < 1025) s += row[j];
            }
#pragma unroll
            for (int off = 32; off; off >>= 1) s += __shfl_xor(s, off, 64);
            if (lane == 0) dinv[r] = 1.0f / sqrtf((float)s + 1.0f);
        }
        return;
    }

    __shared__ float R[4*4*512];   // 32 KB

    if (b < 144) {   // ---- conv (b<128) & lin (128<=b<144): 4-mtile path
        f32x4 acc0[4] = {{0,0,0,0},{0,0,0,0},{0,0,0,0},{0,0,0,0}};
        f32x4 acc1[4] = {{0,0,0,0},{0,0,0,0},{0,0,0,0},{0,0,0,0}};
        int slot, nodebase, mbase;
        if (b < 128) {            // conv: M=512, K=36864; mg=b>>4, ks=b&15
            int mg = b >> 4, ks = b & 15;
            slot = ks; nodebase = 0; mbase = mg*4;
            const float* B0 = conv_enc_w + (size_t)n16*147456;
            const float* B1 = conv_enc_w + (size_t)(16+n16)*147456;
            enc_tile4<18,576>(conv_w + (size_t)mbase*16*36864, 36864,
                              B0, B1, ks*2304 + w*576, n16, kg, acc0, acc1);
        } else {                  // lin: M=256, K=4096; 4 mg x 4 ks
            int bb = b - 128; int mg = bb >> 2, ks = bb & 3;
            slot = ks; nodebase = 512; mbase = mg*4;
            const float* B0 = lin_enc_w + (size_t)n16*16384;
            const float* B1 = lin_enc_w + (size_t)(16+n16)*16384;
            enc_tile4<8,64>(lin_w + (size_t)mbase*16*4096, 4096,
                            B0, B1, ks*1024 + w*256, n16, kg, acc0, acc1);
        }
#pragma unroll
        for (int m = 0; m < 4; ++m)
#pragma unroll
            for (int r = 0; r < 4; ++r) {
                R[((w*4 + m)*16 + kg*4 + r)*32 + n16]      = acc0[m][r];
                R[((w*4 + m)*16 + kg*4 + r)*32 + 16 + n16] = acc1[m][r];
            }
        __syncthreads();
        for (int e = tid; e < 2048; e += 256) {
            int m = e >> 9, wi = e & 511;
            float s = R[m*512 + wi]        + R[(4+m)*512 + wi]
                    + R[(8+m)*512 + wi]    + R[(12+m)*512 + wi];
            int nl = wi >> 5, h = wi & 31;
            int node = nodebase + (mbase + m)*16 + nl;
            P[((size_t)slot*1024 + node)*32 + h] = s;
        }
    } else {         // ---- bias (144<=b<160): single-mtile path
        int mtile = b - 144;
        f32x4 acc0 = {0,0,0,0}, acc1 = {0,0,0,0};
        if (w < 2) {
            const float* Ar = bias_w     + (size_t)(mtile*16 + n16)*64;
            const float* B0 = bias_enc_w + (size_t)n16*128;
            const float* B1 = bias_enc_w + (size_t)(16+n16)*128;
            enc_tile<1,0>(Ar, B0, B1, w*32, kg, acc0, acc1);
        }
#pragma unroll
        for (int r = 0; r < 4; ++r) {
            R[(w*16 + kg*4 + r)*32 + n16]      = acc0[r];
            R[(w*16 + kg*4 + r)*32 + 16 + n16] = acc1[r];
        }
        __syncthreads();
        for (int e = tid; e < 512; e += 256) {
            float s = R[e] + R[512+e] + R[1024+e] + R[1536+e];
            int nl = e >> 5, h = e & 31;
            int node = 768 + mtile*16 + nl;
            P[(size_t)node*32 + h] = s;          // slot 0
        }
    }
}

// ---------------------------------------------------------------------------
// k_z1: R6-exact (ns=16 conv slots; + red zeroing)
// ---------------------------------------------------------------------------
__global__ __launch_bounds__(256) void k_z1(
    const float* __restrict__ P,
    const float* __restrict__ conv_enc_b,
    const float* __restrict__ lin_enc_b,
    const float* __restrict__ bias_enc_b,
    const float* __restrict__ embed_tab,
    const int* __restrict__ prims,
    const float* __restrict__ gcn_w1,
    const float* __restrict__ dinv,
    float* __restrict__ Z1s,
    float* __restrict__ red)
{
    __shared__ float El[8*32], Ml[8*32];
    int tid = threadIdx.x;
    int i0 = blockIdx.x * 8;

    for (int idx = blockIdx.x*256 + tid; idx < 98400; idx += 129*256)
        red[idx] = 0.f;

    {
        int rl = tid >> 5, h = tid & 31;
        int i = i0 + rl;
        if (i < 1025) {
            float e, m;
            if (i == 0) { e = 1.0f; m = 1.0f; }
            else {
                int node = i - 1;
                int ns; float bias;
                if (node < 512)      { ns = 16; bias = conv_enc_b[h]; }
                else if (node < 768) { ns = 4;  bias = lin_enc_b[h];  }
                else                 { ns = 1;  bias = bias_enc_b[h]; }
                float s = bias;
                for (int sl = 0; sl < ns; ++sl)
                    s += P[((size_t)sl*1024 + node)*32 + h];
                e = s;
                m = embed_tab[prims[node]*32 + h];
            }
            El[rl*32+h] = e; Ml[rl*32+h] = m;
        }
    }
    __syncthreads();
    if (tid < 192) {
        int rl = tid / 24, c4 = tid % 24;
        int i = i0 + rl;
        if (i < 1025) {
            float a0=0,a1=0,a2=0,a3=0;
            for (int h = 0; h < 32; ++h) {
                float e = El[rl*32+h], m = Ml[rl*32+h];
                float4 wa = *(const float4*)(gcn_w1 + h*96 + c4*4);
                float4 wb = *(const float4*)(gcn_w1 + (h+32)*96 + c4*4);
                float4 wc = *(const float4*)(gcn_w1 + (h+64)*96 + c4*4);
                a0 += e*(wa.x+wb.x) + m*wc.x;
                a1 += e*(wa.y+wb.y) + m*wc.y;
                a2 += e*(wa.z+wb.z) + m*wc.z;
                a3 += e*(wa.w+wb.w) + m*wc.w;
            }
            float di = dinv[i];
            float* o = Z1s + (size_t)i*96 + c4*4;
            o[0] = di*a0; o[1] = di*a1; o[2] = di*a2; o[3] = di*a3;
        }
    }
}

// ---------------------------------------------------------------------------
// k_propA: R6-exact. 52 i-tiles x 8 j-chunks = 416 blocks; global atomicAdd.
// ---------------------------------------------------------------------------
__global__ __launch_bounds__(256) void k_propA(
    const float* __restrict__ Zs, const int* __restrict__ adj,
    float* __restrict__ red)
{
    __shared__ float adjf[20*132];
    int tid = threadIdx.x;
    int jc = blockIdx.x & 7, it = blockIdx.x >> 3;
    int i0 = it * 20;
    int j0 = jc * 128;
    int jlen = (jc == 7) ? 129 : 128;

    for (int idx = tid; idx < 20*132; idx += 256) {
        int row = idx / 132, c = idx % 132;
        int i = i0 + row, j = j0 + c;
        if (c < jlen && i < 1025)
            adjf[row*132 + c] = (float)adj[(size_t)i*1025 + j]
                                + (i == j ? 1.0f : 0.0f);
    }
    __syncthreads();

    if (tid < 240) {
        int c4 = tid % 24, ig = tid / 24;
        int rA = i0 + ig, rB = i0 + ig + 10;
        float accA[4] = {0,0,0,0}, accB[4] = {0,0,0,0};
        for (int jj = 0; jj < jlen; ++jj) {
            const float4 z = *(const float4*)(Zs + (size_t)(j0+jj)*96 + c4*4);
            float aA = adjf[ig*132 + jj];
            float aB = adjf[(ig+10)*132 + jj];
            accA[0] += aA*z.x; accA[1] += aA*z.y;
            accA[2] += aA*z.z; accA[3] += aA*z.w;
            accB[0] += aB*z.x; accB[1] += aB*z.y;
            accB[2] += aB*z.z; accB[3] += aB*z.w;
        }
        if (rA < 1025) {
            float* o = red + (size_t)rA*96 + c4*4;
            atomicAdd(o+0, accA[0]); atomicAdd(o+1, accA[1]);
            atomicAdd(o+2, accA[2]); atomicAdd(o+3, accA[3]);
        }
        if (rB < 1025) {
            float* o = red + (size_t)rB*96 + c4*4;
            atomicAdd(o+0, accB[0]); atomicAdd(o+1, accB[1]);
            atomicAdd(o+2, accB[2]); atomicAdd(o+3, accB[3]);
        }
    }
}

// ---------------------------------------------------------------------------
// k_propF0: R6-exact. Z2s = dinv*(relu(dinv*red)@W2); re-zeroes red.
// ---------------------------------------------------------------------------
__global__ __launch_bounds__(256) void k_propF0(
    const float* __restrict__ red, const float* __restrict__ dinv,
    const float* __restrict__ gcn_w2,
    float* __restrict__ Z2s, float* __restrict__ redz)
{
    __shared__ float redl[5*96];
    int tid = threadIdx.x;
    int i0 = blockIdx.x * 5;
    for (int idx = tid; idx < 5*96; idx += 256) {
        int r = idx / 96, c = idx % 96;
        int i = i0 + r;
        if (i < 1025) {
            redl[idx] = red[(size_t)i*96 + c];
            redz[(size_t)i*96 + c] = 0.f;
        }
    }
    __syncthreads();
    if (tid < 120) {
        int c4 = tid % 24, ig = tid / 24;
        int i = i0 + ig;
        if (i < 1025) {
            float di = dinv[i];
            float o0=0,o1=0,o2=0,o3=0;
            for (int c = 0; c < 96; ++c) {
                float hv = redl[ig*96 + c] * di; hv = hv > 0.f ? hv : 0.f;
                float4 w2 = *(const float4*)(gcn_w2 + c*96 + c4*4);
                o0 += hv*w2.x; o1 += hv*w2.y; o2 += hv*w2.z; o3 += hv*w2.w;
            }
            float* o = Z2s + (size_t)i*96 + c4*4;
            o[0] = di*o0; o[1] = di*o1; o[2] = di*o2; o[3] = di*o3;
        }
    }
}

// ---------------------------------------------------------------------------
// k_propF1: R6-exact. Xb = bf16(dinv*red).
// ---------------------------------------------------------------------------
__global__ __launch_bounds__(256) void k_propF1(
    const float* __restrict__ red, const float* __restrict__ dinv,
    unsigned short* __restrict__ Xb)
{
    for (int idx = blockIdx.x*256 + threadIdx.x; idx < 98400; idx += 192*256) {
        int r = idx / 96;
        __hip_bfloat16 hb = __float2bfloat16(dinv[r] * red[idx]);
        Xb[idx] = *(unsigned short*)&hb;
    }
}

// ---------------------------------------------------------------------------
// k_dec: R5-exact (direct stores).
// ---------------------------------------------------------------------------
__global__ __launch_bounds__(256) void k_dec(
    const unsigned short* __restrict__ Xb,
    const float* __restrict__ cW, const float* __restrict__ cB,
    const float* __restrict__ lW, const float* __restrict__ lB,
    const float* __restrict__ bW, const float* __restrict__ bB,
    float* __restrict__ out)
{
    int b = blockIdx.x, tid = threadIdx.x;
    int w = tid >> 6, lane = tid & 63;
    int n16 = lane & 15, kg = lane >> 4;

    const float *W, *Bv;
    int g0, kcw, ncols, div, ostride;
    size_t obase;
    if (b < 576) {                       // conv decoder
        int kb = b >> 1, mb = b & 1;
        W = cW; Bv = cB; g0 = 1 + mb*256; kcw = kb*128 + w*32; ncols = 36864;
        div = 576; obase = (size_t)mb*256*36864; ostride = 36864;
    } else if (b < 608) {                // lin decoder
        int kb = b - 576;
        W = lW; Bv = lB; g0 = 513; kcw = kb*128 + w*32; ncols = 4096;
        div = 64; obase = (size_t)18874368; ostride = 4096;
    } else {                             // bias decoder
        W = bW; Bv = bB; g0 = 769; kcw = w*32; ncols = 64;
        div = 0; obase = (size_t)19922944; ostride = 64;
    }
    if (kcw >= ncols) return;

    int kc_a = kcw + n16, kc_b = kcw + 16 + n16;
    int row_a = div ? kc_a + (kc_a/div)*div : kc_a;
    int row_b = div ? kc_b + (kc_b/div)*div : kc_b;
    const float* Wa = W + (size_t)row_a*96 + kg*8;
    const float* Wb = W + (size_t)row_b*96 + kg*8;
    bf16x8 ba0 = cvt8(Wa);
    bf16x8 ba1 = cvt8(Wa + 32);
    bf16x8 ba2 = cvt8(Wa + 64);
    bf16x8 bb0 = cvt8(Wb);
    bf16x8 bb1 = cvt8(Wb + 32);
    bf16x8 bb2 = cvt8(Wb + 64);
    float bva = Bv[row_a], bvb = Bv[row_b];

#pragma unroll 2
    for (int mt = 0; mt < 16; ++mt) {
        const unsigned short* Ar = Xb + (size_t)(g0 + mt*16 + n16)*96 + kg*8;
        bf16x8 a0 = *(const bf16x8*)(Ar);
        bf16x8 a1 = *(const bf16x8*)(Ar + 32);
        bf16x8 a2 = *(const bf16x8*)(Ar + 64);
        f32x4 acc0 = {0.f,0.f,0.f,0.f}, acc1 = {0.f,0.f,0.f,0.f};
        acc0 = MFMA16(a0, ba0, acc0);
        acc0 = MFMA16(a1, ba1, acc0);
        acc0 = MFMA16(a2, ba2, acc0);
        acc1 = MFMA16(a0, bb0, acc1);
        acc1 = MFMA16(a1, bb1, acc1);
        acc1 = MFMA16(a2, bb2, acc1);
#pragma unroll
        for (int r = 0; r < 4; ++r) {
            int node = mt*16 + kg*4 + r;
            out[obase + (size_t)node*ostride + kc_a] = acc0[r] + bva;
            out[obase + (size_t)node*ostride + kc_b] = acc1[r] + bvb;
        }
    }
}

// ---------------------------------------------------------------------------
extern "C" void kernel_launch(void* const* d_in, const int* in_sizes, int n_in,
                              void* d_out, int out_size, void* d_ws, size_t ws_size,
                              hipStream_t stream)
{
    const float* conv_w     = (const float*)d_in[0];
    const float* lin_w      = (const float*)d_in[1];
    const float* bias_w     = (const float*)d_in[2];
    const float* conv_enc_w = (const float*)d_in[3];
    const float* conv_enc_b = (const float*)d_in[4];
    const float* lin_enc_w  = (const float*)d_in[5];
    const float* lin_enc_b  = (const float*)d_in[6];
    const float* bias_enc_w = (const float*)d_in[7];
    const float* bias_enc_b = (const float*)d_in[8];
    const float* gcn_w1     = (const float*)d_in[9];
    const float* gcn_w2     = (const float*)d_in[10];
    const float* conv_dec_w = (const float*)d_in[11];
    const float* conv_dec_b = (const float*)d_in[12];
    const float* lin_dec_w  = (const float*)d_in[13];
    const float* lin_dec_b  = (const float*)d_in[14];
    const float* bias_dec_w = (const float*)d_in[15];
    const float* bias_dec_b = (const float*)d_in[16];
    const float* embed_tab  = (const float*)d_in[17];
    const int*   adj        = (const int*)d_in[18];
    const int*   prims      = (const int*)d_in[19];

    // workspace (floats): P 16*1024*32 | Z1s | Z2s | dinv | Xb(bf16) | red
    float* P    = (float*)d_ws;             // 524288 f = 2 MB
    float* Z1s  = P + (size_t)16*1024*32;   // 98400 f
    float* Z2s  = Z1s + 1025*96;            // 98400 f
    float* dinv = Z2s + 1025*96;            // 1056 f
    unsigned short* Xb = (unsigned short*)(dinv + 1056);  // 98400 bf16
    float* red  = (float*)(Xb + (size_t)1025*96);         // 98400 f

    k_enc<<<224, 256, 0, stream>>>(conv_w, lin_w, bias_w,
                                   conv_enc_w, lin_enc_w, bias_enc_w,
                                   adj, P, dinv);
    k_z1<<<129, 256, 0, stream>>>(P, conv_enc_b, lin_enc_b, bias_enc_b,
                                  embed_tab, prims, gcn_w1, dinv, Z1s, red);
    k_propA<<<416, 256, 0, stream>>>(Z1s, adj, red);
    k_propF0<<<205, 256, 0, stream>>>(red, dinv, gcn_w2, Z2s, red);
    k_propA<<<416, 256, 0, stream>>>(Z2s, adj, red);
    k_propF1<<<192, 256, 0, stream>>>(red, dinv, Xb);
    k_dec<<<609, 256, 0, stream>>>(Xb, conv_dec_w, conv_dec_b,
                                   lin_dec_w, lin_dec_b,
                                   bias_dec_w, bias_dec_b,
                                   (float*)d_out);
}